// Round 1
// baseline (421.255 us; speedup 1.0000x reference)
//
#include <hip/hip_runtime.h>
#include <hip/hip_bf16.h>

// Problem: out[b,t,n,f] = in[b,t,n,f] * (ALPHA+BETA) if n < set_size[b,t] else 0
// B=32, T=64, N=128, F=256. fp32 in/out. Memory-bound elementwise with a
// ragged row mask. One block per (b,t); rows are F=256 floats = 64 float4 =
// exactly one wave's float4 iteration, so the mask branch is wave-uniform.
// Masked-out rows skip the input read entirely (write zeros only).

#define N_DIM 128
#define F_DIM 256
#define ROW_F4 (F_DIM / 4)              // 64 float4 per row
#define BT_F4 (N_DIM * ROW_F4)          // 8192 float4 per (b,t)
#define BLOCK 256
#define SCALE 1.1f                      // ALPHA + BETA

__global__ __launch_bounds__(BLOCK) void mask_scale_kernel(
    const float4* __restrict__ in,
    const int* __restrict__ sizes,
    float4* __restrict__ out) {
    const int bt = blockIdx.x;                // 0 .. B*T-1
    const int set = sizes[bt];                // wave-uniform (blockIdx-based)
    const long long base = (long long)bt * BT_F4;

    // 8192 float4 / 256 threads = 32 iterations; each wave-iteration covers
    // exactly one n-row -> branch is wave-uniform, no divergence.
#pragma unroll 4
    for (int j = threadIdx.x; j < BT_F4; j += BLOCK) {
        const int n = j >> 6;                 // j / ROW_F4
        const long long idx = base + j;
        if (n < set) {
            float4 v = in[idx];
            v.x *= SCALE; v.y *= SCALE; v.z *= SCALE; v.w *= SCALE;
            out[idx] = v;
        } else {
            out[idx] = make_float4(0.f, 0.f, 0.f, 0.f);
        }
    }
}

extern "C" void kernel_launch(void* const* d_in, const int* in_sizes, int n_in,
                              void* d_out, int out_size, void* d_ws, size_t ws_size,
                              hipStream_t stream) {
    const float4* in = (const float4*)d_in[0];
    const int* sizes = (const int*)d_in[1];
    float4* out = (float4*)d_out;

    const int bt_count = in_sizes[1];         // B*T = 2048
    mask_scale_kernel<<<bt_count, BLOCK, 0, stream>>>(in, sizes, out);
}

// Round 3
// 409.398 us; speedup vs baseline: 1.0290x; 1.0290x over previous
//
#include <hip/hip_runtime.h>
#include <hip/hip_bf16.h>

// out[b,t,n,f] = in[b,t,n,f] * 1.1 if n < set_size[b,t] else 0
// B=32, T=64, N=128, F=256, fp32. Pure streaming, zero reuse -> nontemporal
// loads/stores to keep the 256MB input + 256MB output out of L2/L3.
// One block per (b,t). Two branch-free loops: scaled rows then zero rows.
// NOTE: __builtin_nontemporal_* needs a native vector type, not HIP float4.

typedef float vfloat4 __attribute__((ext_vector_type(4)));

#define N_DIM 128
#define F_DIM 256
#define ROW_F4 (F_DIM / 4)              // 64 vfloat4 per row
#define BT_F4 (N_DIM * ROW_F4)          // 8192 vfloat4 per (b,t)
#define BLOCK 256
#define SCALE 1.1f                      // ALPHA + BETA

__global__ __launch_bounds__(BLOCK) void mask_scale_kernel(
    const vfloat4* __restrict__ in,
    const int* __restrict__ sizes,
    vfloat4* __restrict__ out) {
    const int bt = blockIdx.x;                 // 0 .. B*T-1
    const int set = sizes[bt];                 // wave-uniform
    const long long base = (long long)bt * BT_F4;
    const int split = set * ROW_F4;            // first vfloat4 of the zero region

    const vfloat4* in_b = in + base;
    vfloat4* out_b = out + base;

    // Region 1: rows [0, set) — read, scale, store. Streaming, nontemporal.
#pragma unroll 4
    for (int j = threadIdx.x; j < split; j += BLOCK) {
        vfloat4 v = __builtin_nontemporal_load(&in_b[j]);
        v *= SCALE;
        __builtin_nontemporal_store(v, &out_b[j]);
    }

    // Region 2: rows [set, 128) — zero-fill only, no input read.
    const vfloat4 z = (vfloat4)(0.f);
#pragma unroll 4
    for (int j = split + (int)threadIdx.x; j < BT_F4; j += BLOCK) {
        __builtin_nontemporal_store(z, &out_b[j]);
    }
}

extern "C" void kernel_launch(void* const* d_in, const int* in_sizes, int n_in,
                              void* d_out, int out_size, void* d_ws, size_t ws_size,
                              hipStream_t stream) {
    const vfloat4* in = (const vfloat4*)d_in[0];
    const int* sizes = (const int*)d_in[1];
    vfloat4* out = (vfloat4*)d_out;

    const int bt_count = in_sizes[1];          // B*T = 2048
    mask_scale_kernel<<<bt_count, BLOCK, 0, stream>>>(in, sizes, out);
}